// Round 4
// baseline (3630.783 us; speedup 1.0000x reference)
//
#include <hip/hip_runtime.h>
#include <stdint.h>

#define B_ 256
#define P_ 620
#define C_ 512
#define T_ 32
#define V_ 140
#define H_ 256
#define A_ 256
#define KC 672   // padded concat K: 140(x) + 256(ctx) + 256(h) = 652 -> 672 = 21*32
#define LOG2E 1.4426950408889634f
#define NLDSP 64          // attn positions resident in LDS
#define NREGIT 18         // reg-resident iters: positions 64 + pbase + it*32

typedef unsigned short u16;
typedef __attribute__((ext_vector_type(8))) short bf16x8;
typedef __attribute__((ext_vector_type(4))) float f32x4;

__device__ __forceinline__ float bf2f(u16 u) {
  union { unsigned int i; float f; } v; v.i = ((unsigned int)u) << 16; return v.f;
}
__device__ __forceinline__ float bfu_lo(unsigned int u) {
  union { unsigned int i; float f; } v; v.i = u << 16; return v.f;
}
__device__ __forceinline__ float bfu_hi(unsigned int u) {
  union { unsigned int i; float f; } v; v.i = u & 0xffff0000u; return v.f;
}
__device__ __forceinline__ u16 f2bf(float f) {
  union { float f; unsigned int i; } v; v.f = f;
  unsigned int x = v.i;
  return (u16)((x + 0x7fffu + ((x >> 16) & 1u)) >> 16);
}
__device__ __forceinline__ float sigf(float x) {
  return 1.f / (1.f + __builtin_exp2f(-x * LOG2E));
}
__device__ __forceinline__ float tanhfast(float x) {
  return 1.f - 2.f / (__builtin_exp2f(2.f * LOG2E * x) + 1.f);
}
__device__ __forceinline__ float ld_any(const void* p, size_t idx, int f32) {
  return f32 ? ((const float*)p)[idx] : bf2f(((const u16*)p)[idx]);
}
__device__ __forceinline__ bf16x8 ld8_any(const void* base, size_t off, int f32) {
  if (f32) {
    const float4* p = (const float4*)((const float*)base + off);
    float4 x = p[0], y = p[1];
    bf16x8 r;
    r[0] = (short)f2bf(x.x); r[1] = (short)f2bf(x.y);
    r[2] = (short)f2bf(x.z); r[3] = (short)f2bf(x.w);
    r[4] = (short)f2bf(y.x); r[5] = (short)f2bf(y.y);
    r[6] = (short)f2bf(y.z); r[7] = (short)f2bf(y.w);
    return r;
  }
  return *(const bf16x8*)((const u16*)base + off);
}
// dot of 8 bf16 weights (uint4) against 8 f32 inputs (two float4)
__device__ __forceinline__ float dot8(uint4 u, float4 iA, float4 iB) {
  return bfu_lo(u.x) * iA.x + bfu_hi(u.x) * iA.y
       + bfu_lo(u.y) * iA.z + bfu_hi(u.y) * iA.w
       + bfu_lo(u.z) * iB.x + bfu_hi(u.z) * iB.y
       + bfu_lo(u.w) * iB.z + bfu_hi(u.w) * iB.w;
}

// ---------------- dtype detection: low u16 halves of f32 words are garbage ---
__global__ void k_detect(const unsigned int* __restrict__ img, int* __restrict__ flag) {
  __shared__ int mx[256];
  unsigned int u = img[threadIdx.x];
  mx[threadIdx.x] = (int)((u >> 7) & 0xffu);  // bf16 exponent of LOW u16
  __syncthreads();
  if (threadIdx.x == 0) {
    int m = 0;
    #pragma unroll 16
    for (int i = 0; i < 256; i++) m = (mx[i] > m) ? mx[i] : m;
    *flag = (m >= 0x90) ? 1 : 0;  // bf16 N(0,1) data never reaches 2^17
  }
}

// ---------------- init: coalesced weight layouts ----------------------------
// W2[((kk*4 + blk)*256 + r)*8 + e] = W_cat[jq = blk*256+r][kk*8+e]
//   (W_cat row jq = j*4+q <-> orig gate row n = q*256+j ; cols [W_ih|W_hh|0])
// Hc_p[j2*256 + n] = pack(bf16(Hc_w[n][2j2]), bf16(Hc_w[n][2j2+1]))
// Cd_p[j2*140 + v] = pack(bf16(Cd_w[v][2j2]), bf16(Cd_w[v][2j2+1]))
__global__ void k_init(const void* __restrict__ W_ih, const void* __restrict__ W_hh,
                       const void* __restrict__ b_ih, const void* __restrict__ b_hh,
                       const void* __restrict__ Hc_w, const void* __restrict__ Hc_b,
                       const void* __restrict__ Cd_w, const void* __restrict__ Cd_b,
                       u16* __restrict__ W2, float* __restrict__ bias_cat,
                       unsigned int* __restrict__ Hc_p, float* __restrict__ hcb_f,
                       unsigned int* __restrict__ Cd_p, float* __restrict__ cdb_f,
                       const int* __restrict__ flag) {
  const int f32 = *flag;
  const int tid = blockIdx.x * blockDim.x + threadIdx.x;
  const int nthr = gridDim.x * blockDim.x;
  // output-major: coalesced W2 writes
  for (int idx = tid; idx < 1024 * KC; idx += nthr) {
    const int e = idx & 7, rr = (idx >> 3) & 255, blk = (idx >> 11) & 3, kk = idx >> 13;
    const int k = kk * 8 + e, jq = blk * 256 + rr;
    const int j = jq >> 2, q = jq & 3, n = q * H_ + j;
    u16 v = 0;
    if (k < 396) v = f2bf(ld_any(W_ih, (size_t)n * 396 + k, f32));
    else if (k < 652) v = f2bf(ld_any(W_hh, (size_t)n * H_ + (k - 396), f32));
    W2[idx] = v;
  }
  for (int n = tid; n < 1024; n += nthr) {
    int j = n >> 2, q = n & 3, on = q * H_ + j;
    bias_cat[n] = ld_any(b_ih, on, f32) + ld_any(b_hh, on, f32);
  }
  for (int idx = tid; idx < 128 * 256; idx += nthr) {
    int j2 = idx >> 8, n = idx & 255;
    u16 lo = f2bf(ld_any(Hc_w, (size_t)n * H_ + 2 * j2, f32));
    u16 hi = f2bf(ld_any(Hc_w, (size_t)n * H_ + 2 * j2 + 1, f32));
    Hc_p[idx] = (unsigned int)lo | ((unsigned int)hi << 16);
  }
  for (int idx = tid; idx < 128 * 140; idx += nthr) {
    int j2 = idx / 140, v = idx - j2 * 140;
    u16 lo = f2bf(ld_any(Cd_w, (size_t)v * H_ + 2 * j2, f32));
    u16 hi = f2bf(ld_any(Cd_w, (size_t)v * H_ + 2 * j2 + 1, f32));
    Cd_p[idx] = (unsigned int)lo | ((unsigned int)hi << 16);
  }
  for (int n = tid; n < A_; n += nthr) hcb_f[n] = ld_any(Hc_b, n, f32);
  for (int n = tid; n < V_; n += nthr) cdb_f[n] = ld_any(Cd_b, n, f32);
}

// ---------------- phase 1: attn_img = img @ Ic_w^T + Ic_b (bf16 out) ---------
__global__ __launch_bounds__(256) void k_proj(const void* __restrict__ img,
                                              const void* __restrict__ Ic_w,
                                              const void* __restrict__ Ic_b,
                                              u16* __restrict__ attn_img,
                                              const int* __restrict__ flag) {
  __shared__ __align__(16) short As[128 * 32];
  __shared__ __align__(16) short Bs[128 * 32];
  const int f32 = *flag;
  const int tid = threadIdx.x;
  const int lane = tid & 63, w = tid >> 6;
  const int wg = blockIdx.x;
  const int m0 = ((wg & 7) + (wg >> 4) * 8) * 128;
  const int n0 = ((wg >> 3) & 1) * 128;
  f32x4 acc[4][4] = {};
  const int wm = w & 1, wn = w >> 1;
  const int fr = lane & 15, fq = lane >> 4;
  const int srow = tid >> 2, scol = (tid & 3) * 8;
  for (int kt = 0; kt < C_; kt += 32) {
    bf16x8 a0 = ld8_any(img, (size_t)(m0 + srow) * C_ + kt + scol, f32);
    bf16x8 a1 = ld8_any(img, (size_t)(m0 + srow + 64) * C_ + kt + scol, f32);
    bf16x8 b0 = ld8_any(Ic_w, (size_t)(n0 + srow) * C_ + kt + scol, f32);
    bf16x8 b1 = ld8_any(Ic_w, (size_t)(n0 + srow + 64) * C_ + kt + scol, f32);
    __syncthreads();
    *(bf16x8*)(As + tid * 8) = a0;
    *(bf16x8*)(As + (tid + 256) * 8) = a1;
    *(bf16x8*)(Bs + tid * 8) = b0;
    *(bf16x8*)(Bs + (tid + 256) * 8) = b1;
    __syncthreads();
    bf16x8 af[4], bfr[4];
    #pragma unroll
    for (int i = 0; i < 4; i++)
      af[i] = *(const bf16x8*)(As + (wm * 64 + i * 16 + fr) * 32 + fq * 8);
    #pragma unroll
    for (int j = 0; j < 4; j++)
      bfr[j] = *(const bf16x8*)(Bs + (wn * 64 + j * 16 + fr) * 32 + fq * 8);
    #pragma unroll
    for (int i = 0; i < 4; i++)
      #pragma unroll
      for (int j = 0; j < 4; j++)
        acc[i][j] = __builtin_amdgcn_mfma_f32_16x16x32_bf16(af[i], bfr[j], acc[i][j], 0, 0, 0);
  }
  #pragma unroll
  for (int i = 0; i < 4; i++) {
    #pragma unroll
    for (int j = 0; j < 4; j++) {
      const int col = n0 + wn * 64 + j * 16 + fr;
      const float bias = ld_any(Ic_b, col, f32);
      #pragma unroll
      for (int rr = 0; rr < 4; rr++) {
        const int row = m0 + wm * 64 + i * 16 + fq * 4 + rr;
        attn_img[(size_t)row * A_ + col] = f2bf(acc[i][j][rr] + bias);
      }
    }
  }
}

// score+accumulate for one position held as two uint4 (16 bf16-pairs = 256 col)
#define ACCUM(U0, U1, VALID) do {                                              \
  const float v0 = bfu_lo((U0).x), v1 = bfu_hi((U0).x);                        \
  const float v2 = bfu_lo((U0).y), v3 = bfu_hi((U0).y);                        \
  const float v4 = bfu_lo((U0).z), v5 = bfu_hi((U0).z);                        \
  const float v6 = bfu_lo((U0).w), v7 = bfu_hi((U0).w);                        \
  const float v8 = bfu_lo((U1).x), v9 = bfu_hi((U1).x);                        \
  const float va = bfu_lo((U1).y), vb = bfu_hi((U1).y);                        \
  const float vc = bfu_lo((U1).z), vd = bfu_hi((U1).z);                        \
  const float ve = bfu_lo((U1).w), vf = bfu_hi((U1).w);                        \
  float s = qr[0]*v0 + qr[1]*v1 + qr[2]*v2 + qr[3]*v3                          \
          + qr[4]*v4 + qr[5]*v5 + qr[6]*v6 + qr[7]*v7                          \
          + qr[8]*v8 + qr[9]*v9 + qr[10]*va + qr[11]*vb                        \
          + qr[12]*vc + qr[13]*vd + qr[14]*ve + qr[15]*vf;                     \
  s += __shfl_xor(s, 1); s += __shfl_xor(s, 2);                                \
  s += __shfl_xor(s, 4); s += __shfl_xor(s, 8);                                \
  const float es = (VALID) ? __builtin_exp2f(s * sc - 16.f) : 0.f;             \
  l_acc += es;                                                                 \
  cx[0] += es*v0; cx[1] += es*v1; cx[2] += es*v2; cx[3] += es*v3;              \
  cx[4] += es*v4; cx[5] += es*v5; cx[6] += es*v6; cx[7] += es*v7;              \
  cx[8] += es*v8; cx[9] += es*v9; cx[10] += es*va; cx[11] += es*vb;            \
  cx[12] += es*vc; cx[13] += es*vd; cx[14] += es*ve; cx[15] += es*vf;          \
} while (0)

// ---------------- persistent recurrence: one block per batch -----------------
// attn_img slice resident: 64 positions in LDS (32 KB) + 556 in registers
// (ar0/ar1[18], ~144 VGPR packed bf16). Re-read cost across 32 steps: ZERO.
// Per-step memory = W (L2) + Hc/Cd (L2) only -> L2-BW floor ~12 us/step.
__global__ __launch_bounds__(512, 2) void k_seq(
    const unsigned int* __restrict__ Hc_p, const float* __restrict__ hcb_f,
    const unsigned int* __restrict__ Cd_p, const float* __restrict__ cdb_f,
    const u16* __restrict__ W2, const float* __restrict__ bias_cat,
    const u16* __restrict__ attn_img, const void* __restrict__ targets,
    void* __restrict__ d_out, const int* __restrict__ flag) {
  __shared__ __align__(16) uint4 attn_lds[NLDSP * 32];   // 32 KB
  __shared__ float h_s[H_];
  __shared__ float q_s[A_];
  __shared__ __align__(16) float inp_s[KC];   // [x(140) | ctx(256) | h(256) | 0pad]
  __shared__ __align__(16) float ctx_s[8][A_];
  __shared__ float red_l[8];
  __shared__ __align__(16) float gpart[1024]; // permuted gate rows jq=j*4+q
  const int f32 = *flag;
  const int b = blockIdx.x;
  const int tid = threadIdx.x;
  const int lane = tid & 63, w = tid >> 6;
  const int l16 = lane & 15, g = lane >> 4;
  const int pbase = w * 4 + g;                // this 16-lane group's position slot
  const uint4* wb = (const uint4*)W2;         // index (kk*4+blk)*256 + r
  const int blk = tid >> 8, rr = tid & 255;   // gate rows jq: tid and tid+512

  // ---- prologue: resident attn_img load (once; reused all 32 steps) ----
  const uint4* ap = (const uint4*)(attn_img + (size_t)b * P_ * A_);
  uint4 ar0[NREGIT], ar1[NREGIT];
  #pragma unroll
  for (int it = 0; it < NREGIT; it++) {
    int p = NLDSP + pbase + it * 32;
    int pc = (p < P_) ? p : (P_ - 1);
    ar0[it] = ap[(size_t)pc * 32 + l16];
    ar1[it] = ap[(size_t)pc * 32 + 16 + l16];
  }
  for (int i = tid; i < NLDSP * 32; i += 512) attn_lds[i] = ap[i];

  if (tid < H_) h_s[tid] = 0.f;
  for (int i = tid; i < KC; i += 512) inp_s[i] = 0.f;
  if (tid < V_) inp_s[tid] = ld_any(targets, (size_t)b * T_ * V_ + tid, f32);
  float c_reg = 0.f;                          // thread tid<256 owns c[tid]
  const float bias0 = bias_cat[tid];
  const float bias1 = bias_cat[tid + 512];
  const float sc = 0.0625f * LOG2E;           // 1/sqrt(A) folded with log2(e)
  __syncthreads();

  for (int t = 0; t < T_; t++) {
    // ---- P1: q = h@Hc^T + b (tid<256) ; out_{t-1} = h@Cd^T + b (256..395) ---
    if (tid < A_) {
      float acc = hcb_f[tid];
      #pragma unroll 8
      for (int j2 = 0; j2 < H_ / 2; j2++) {
        const unsigned int u = Hc_p[j2 * 256 + tid];
        acc += bfu_lo(u) * h_s[2 * j2] + bfu_hi(u) * h_s[2 * j2 + 1];
      }
      q_s[tid] = acc;
    } else if (t > 0 && tid < A_ + V_) {
      const int v = tid - A_;
      float acc = cdb_f[v];
      #pragma unroll 8
      for (int j2 = 0; j2 < H_ / 2; j2++) {
        const unsigned int u = Cd_p[j2 * 140 + v];
        acc += bfu_lo(u) * h_s[2 * j2] + bfu_hi(u) * h_s[2 * j2 + 1];
      }
      const size_t oo = (size_t)b * T_ * V_ + (size_t)(t - 1) * V_ + v;
      if (f32) ((float*)d_out)[oo] = acc;
      else ((u16*)d_out)[oo] = f2bf(acc);
      inp_s[v] = acc;  // x_t = out_{t-1}
    }
    __syncthreads();  // barrier A

    // hoist first gate-chunk loads (step-invariant addresses) under attn VALU
    uint4 ga0 = wb[(0 * 4 + blk) * 256 + rr];
    uint4 ga1 = wb[(0 * 4 + 2 + blk) * 256 + rr];

    // ---- P2a: attention over resident data (pure VALU/LDS), all 8 waves ----
    float l_acc = 0.f;
    float cx[16] = {};
    {
      float qr[16];
      #pragma unroll
      for (int e = 0; e < 8; e++) {
        qr[e] = q_s[l16 * 8 + e];
        qr[8 + e] = q_s[128 + l16 * 8 + e];
      }
      #pragma unroll
      for (int it = 0; it < 2; it++) {
        const int p = pbase + it * 32;
        const uint4 u0 = attn_lds[p * 32 + l16];
        const uint4 u1 = attn_lds[p * 32 + 16 + l16];
        ACCUM(u0, u1, true);
      }
      #pragma unroll
      for (int it = 0; it < NREGIT - 1; it++) ACCUM(ar0[it], ar1[it], true);
      ACCUM(ar0[NREGIT - 1], ar1[NREGIT - 1], pbase < 12);  // tail mask: p>=620
      #pragma unroll
      for (int k = 0; k < 16; k++) {
        cx[k] += __shfl_xor(cx[k], 16);
        cx[k] += __shfl_xor(cx[k], 32);
      }
      l_acc += __shfl_xor(l_acc, 16);
      l_acc += __shfl_xor(l_acc, 32);
      if (g == 0) {
        #pragma unroll
        for (int e = 0; e < 8; e++) {
          ctx_s[w][l16 * 8 + e] = cx[e];
          ctx_s[w][128 + l16 * 8 + e] = cx[8 + e];
        }
        if (l16 == 0) red_l[w] = l_acc;
      }
    }

    // ---- P2b: gates xh-partial, rows {tid, tid+512}, chunks 0..16 & 50..83 --
    float g0 = bias0, g1 = bias1;   // stays in registers across barriers B,C
    {
      int ck = 0;
      #pragma unroll 3
      for (int i = 0; i < 51; i++) {
        const int ni = (i + 1 < 51) ? i + 1 : 50;
        const int nk = (ni < 17) ? ni : ni + 33;
        const uint4 b0v = wb[(nk * 4 + blk) * 256 + rr];
        const uint4 b1v = wb[(nk * 4 + 2 + blk) * 256 + rr];
        const float4 iA = *(const float4*)(inp_s + ck * 8);
        const float4 iB = *(const float4*)(inp_s + ck * 8 + 4);
        g0 += dot8(ga0, iA, iB);
        g1 += dot8(ga1, iA, iB);
        ga0 = b0v; ga1 = b1v; ck = nk;
      }
    }
    __syncthreads();  // barrier B

    // ---- P3a: finalize ctx -> inp_s[140..395] ----
    if (tid < A_) {
      float l = red_l[0];
      float cv = ctx_s[0][tid];
      #pragma unroll
      for (int i = 1; i < 8; i++) { l += red_l[i]; cv += ctx_s[i][tid]; }
      inp_s[V_ + tid] = cv / l;
    }
    __syncthreads();  // barrier C

    // ---- P3b: gates ctx-part, same rows, chunks 17..49 ----
    {
      uint4 a0 = wb[(17 * 4 + blk) * 256 + rr];
      uint4 a1 = wb[(17 * 4 + 2 + blk) * 256 + rr];
      #pragma unroll 4
      for (int kk = 17; kk < 50; kk++) {
        const int nk = (kk + 1 < 50) ? kk + 1 : 49;
        const uint4 b0v = wb[(nk * 4 + blk) * 256 + rr];
        const uint4 b1v = wb[(nk * 4 + 2 + blk) * 256 + rr];
        const float4 iA = *(const float4*)(inp_s + kk * 8);
        const float4 iB = *(const float4*)(inp_s + kk * 8 + 4);
        g0 += dot8(a0, iA, iB);
        g1 += dot8(a1, iA, iB);
        a0 = b0v; a1 = b1v;
      }
      gpart[tid] = g0;
      gpart[tid + 512] = g1;
    }
    __syncthreads();  // barrier D

    // ---- cell: thread tid<256 owns hidden j = tid ----
    if (tid < H_) {
      const float4 g4 = *(const float4*)(gpart + 4 * tid);  // [i,f,g,o]
      const float is = sigf(g4.x), fs = sigf(g4.y);
      const float gt = tanhfast(g4.z), os = sigf(g4.w);
      const float cn = fs * c_reg + is * gt;
      const float h2 = os * tanhfast(cn);
      c_reg = cn;
      h_s[tid] = h2;
      inp_s[V_ + A_ + tid] = h2;
    }
    __syncthreads();  // barrier E
  }

  // ---- final out for t = T-1 ----
  if (tid < V_) {
    float acc = cdb_f[tid];
    #pragma unroll 8
    for (int j2 = 0; j2 < H_ / 2; j2++) {
      const unsigned int u = Cd_p[j2 * 140 + tid];
      acc += bfu_lo(u) * h_s[2 * j2] + bfu_hi(u) * h_s[2 * j2 + 1];
    }
    const size_t oo = (size_t)b * T_ * V_ + (size_t)(T_ - 1) * V_ + tid;
    if (f32) ((float*)d_out)[oo] = acc;
    else ((u16*)d_out)[oo] = f2bf(acc);
  }
}

extern "C" void kernel_launch(void* const* d_in, const int* in_sizes, int n_in,
                              void* d_out, int out_size, void* d_ws, size_t ws_size,
                              hipStream_t stream) {
  (void)in_sizes; (void)n_in; (void)out_size; (void)ws_size;
  const void* img  = d_in[0];
  const void* tgt  = d_in[1];
  const void* Ic_w = d_in[2];
  const void* Ic_b = d_in[3];
  const void* Hc_w = d_in[4];
  const void* Hc_b = d_in[5];
  const void* W_ih = d_in[6];
  const void* W_hh = d_in[7];
  const void* b_ih = d_in[8];
  const void* b_hh = d_in[9];
  const void* Cd_w = d_in[10];
  const void* Cd_b = d_in[11];

  char* ws = (char*)d_ws;
  size_t off = 0;
  auto alloc = [&](size_t bytes) -> void* {
    void* p = ws + off;
    off += (bytes + 255) & ~(size_t)255;
    return p;
  };
  u16*   attn_img = (u16*)alloc((size_t)B_ * P_ * A_ * 2);
  u16*   W2       = (u16*)alloc((size_t)1024 * KC * 2);
  float* bias_cat = (float*)alloc(1024 * 4);
  unsigned int* Hc_p = (unsigned int*)alloc((size_t)128 * 256 * 4);
  float* hcb_f    = (float*)alloc(A_ * 4);
  unsigned int* Cd_p = (unsigned int*)alloc((size_t)128 * 140 * 4);
  float* cdb_f    = (float*)alloc(V_ * 4);
  int*   flag     = (int*)alloc(256);

  k_detect<<<dim3(1), dim3(256), 0, stream>>>((const unsigned int*)img, flag);
  k_init<<<dim3(512), dim3(256), 0, stream>>>(W_ih, W_hh, b_ih, b_hh,
                                              Hc_w, Hc_b, Cd_w, Cd_b,
                                              W2, bias_cat,
                                              Hc_p, hcb_f, Cd_p, cdb_f, flag);
  k_proj<<<dim3(2480), dim3(256), 0, stream>>>(img, Ic_w, Ic_b, attn_img, flag);
  k_seq<<<dim3(B_), dim3(512), 0, stream>>>(Hc_p, hcb_f, Cd_p, cdb_f,
                                            W2, bias_cat, attn_img, tgt, d_out, flag);
}